// Round 1
// baseline (578.260 us; speedup 1.0000x reference)
//
#include <hip/hip_runtime.h>

#define NN 100000
#define EE 1600000
#define CH 128

// ---------------- CSR build (dst-sorted, self-loops appended) ----------------

__global__ __launch_bounds__(256) void k_count(const int* __restrict__ dst, int* __restrict__ cnt) {
    int i = blockIdx.x * 256 + threadIdx.x;
    if (i < EE) atomicAdd(&cnt[dst[i]], 1);
}

// exclusive scan of sizes (cnt[i]+1), 1024 elems/block
__global__ __launch_bounds__(256) void k_scan1(const int* __restrict__ cnt, int* __restrict__ rp,
                                               int* __restrict__ bsum) {
    __shared__ int ts[256];
    int tid = threadIdx.x;
    int base = blockIdx.x * 1024 + tid * 4;
    int v[4]; int s = 0;
#pragma unroll
    for (int j = 0; j < 4; ++j) { int i = base + j; v[j] = s; s += (i < NN) ? (cnt[i] + 1) : 0; }
    ts[tid] = s; __syncthreads();
    for (int off = 1; off < 256; off <<= 1) {
        int t = (tid >= off) ? ts[tid - off] : 0;
        __syncthreads();
        ts[tid] += t;
        __syncthreads();
    }
    int excl = ts[tid] - s;
#pragma unroll
    for (int j = 0; j < 4; ++j) { int i = base + j; if (i < NN) rp[i] = excl + v[j]; }
    if (tid == 255) bsum[blockIdx.x] = ts[255];
}

__global__ __launch_bounds__(256) void k_scan2(int* __restrict__ bsum, int nb) {
    __shared__ int ts[256];
    int tid = threadIdx.x;
    int v = (tid < nb) ? bsum[tid] : 0;
    ts[tid] = v; __syncthreads();
    for (int off = 1; off < 256; off <<= 1) {
        int t = (tid >= off) ? ts[tid - off] : 0;
        __syncthreads();
        ts[tid] += t;
        __syncthreads();
    }
    if (tid < nb) bsum[tid] = ts[tid] - v;
}

__global__ __launch_bounds__(256) void k_scan3(int* __restrict__ rp, const int* __restrict__ bsum,
                                               const int* __restrict__ cnt, float* __restrict__ dinv) {
    int i = blockIdx.x * 256 + threadIdx.x;
    if (i < NN) {
        rp[i] += bsum[i >> 10];
        dinv[i] = rsqrtf((float)(cnt[i] + 1));
    }
    if (i == NN) rp[NN] = EE + NN;
}

__global__ __launch_bounds__(256) void k_fill(const int* __restrict__ src, const int* __restrict__ dst,
                                              const int* __restrict__ rp, int* __restrict__ cur,
                                              int* __restrict__ col) {
    int i = blockIdx.x * 256 + threadIdx.x;
    if (i >= EE + NN) return;
    int s, d;
    if (i < EE) { s = src[i]; d = dst[i]; } else { s = d = i - EE; }
    int pos = rp[d] + atomicAdd(&cur[d], 1);
    col[pos] = s;
}

// ---------------- BN param fold: scale = g*rsqrt(rv+eps); shift = (b-rm)*scale + be ----------------

__global__ __launch_bounds__(128) void k_bn(const float* __restrict__ b, const float* __restrict__ g,
                                            const float* __restrict__ be, const float* __restrict__ rm,
                                            const float* __restrict__ rv, float* __restrict__ sc,
                                            float* __restrict__ sh) {
    int t = threadIdx.x;
    float s = g[t] * rsqrtf(rv[t] + 1e-5f);
    sc[t] = s;
    sh[t] = (b[t] - rm[t]) * s + be[t];
}

// ---------------- GEMM [N,128]@[128,128], epilogue: row *= dinv[row] ----------------

__global__ __launch_bounds__(256) void k_gemm128(const float* __restrict__ A, const float* __restrict__ W,
                                                 const float* __restrict__ dinv, float* __restrict__ C,
                                                 int nrows) {
    __shared__ float Ws[CH * CH];  // 64 KB
    {
        const float4* wv = (const float4*)W;
        float4* sv = (float4*)Ws;
#pragma unroll
        for (int i = 0; i < 16; ++i) sv[threadIdx.x + 256 * i] = wv[threadIdx.x + 256 * i];
    }
    __syncthreads();
    int tx = threadIdx.x & 15, ty = threadIdx.x >> 4;
    int row0 = blockIdx.x * 64 + ty * 4, col0 = tx * 8;
    int r[4];
#pragma unroll
    for (int j = 0; j < 4; ++j) { int rr = row0 + j; r[j] = (rr < nrows) ? rr : (nrows - 1); }
    float acc[4][8] = {};
    for (int k4 = 0; k4 < 32; ++k4) {
        float4 a4[4];
#pragma unroll
        for (int j = 0; j < 4; ++j) a4[j] = *(const float4*)(A + (size_t)r[j] * CH + k4 * 4);
#pragma unroll
        for (int kk = 0; kk < 4; ++kk) {
            const float4 w0 = *(const float4*)(Ws + (k4 * 4 + kk) * CH + col0);
            const float4 w1 = *(const float4*)(Ws + (k4 * 4 + kk) * CH + col0 + 4);
#pragma unroll
            for (int j = 0; j < 4; ++j) {
                float av = (&a4[j].x)[kk];
                acc[j][0] += av * w0.x; acc[j][1] += av * w0.y;
                acc[j][2] += av * w0.z; acc[j][3] += av * w0.w;
                acc[j][4] += av * w1.x; acc[j][5] += av * w1.y;
                acc[j][6] += av * w1.z; acc[j][7] += av * w1.w;
            }
        }
    }
#pragma unroll
    for (int j = 0; j < 4; ++j) {
        int rr = row0 + j;
        if (rr < nrows) {
            float dv = dinv[rr];
            float4 o0 = make_float4(acc[j][0] * dv, acc[j][1] * dv, acc[j][2] * dv, acc[j][3] * dv);
            float4 o1 = make_float4(acc[j][4] * dv, acc[j][5] * dv, acc[j][6] * dv, acc[j][7] * dv);
            *(float4*)(C + (size_t)rr * CH + col0) = o0;
            *(float4*)(C + (size_t)rr * CH + col0 + 4) = o1;
        }
    }
}

// ---------------- Aggregation, 128ch: one wave per node, epilogue fused dinv+BN+ReLU ----------------

__global__ __launch_bounds__(256) void k_agg128(const float* __restrict__ h, const int* __restrict__ rp,
                                                const int* __restrict__ col, const float* __restrict__ dinv,
                                                const float* __restrict__ sc, const float* __restrict__ sh,
                                                float* __restrict__ out) {
    int node = blockIdx.x * 4 + (threadIdx.x >> 6);
    if (node >= NN) return;
    node = __builtin_amdgcn_readfirstlane(node);
    int lane = threadIdx.x & 63;
    int beg = rp[node], end = rp[node + 1];
    float2 acc = make_float2(0.f, 0.f);
    int e = beg;
    for (; e + 2 <= end; e += 2) {
        int s0 = col[e], s1 = col[e + 1];
        const float2 h0 = *(const float2*)(h + (size_t)s0 * CH + lane * 2);
        const float2 h1 = *(const float2*)(h + (size_t)s1 * CH + lane * 2);
        acc.x += h0.x + h1.x;
        acc.y += h0.y + h1.y;
    }
    if (e < end) {
        int s0 = col[e];
        const float2 h0 = *(const float2*)(h + (size_t)s0 * CH + lane * 2);
        acc.x += h0.x;
        acc.y += h0.y;
    }
    float dv = dinv[node];
    int c = lane * 2;
    float2 scv = *(const float2*)(sc + c);
    float2 shv = *(const float2*)(sh + c);
    float o0 = fmaxf(fmaf(acc.x * dv, scv.x, shv.x), 0.f);
    float o1 = fmaxf(fmaf(acc.y * dv, scv.y, shv.y), 0.f);
    *(float2*)(out + (size_t)node * CH + c) = make_float2(o0, o1);
}

// ---------------- Layer 3: [N,128]@[128,2], epilogue dinv; then agg over 2ch + bias ----------------

__global__ __launch_bounds__(256) void k_gemm_out(const float* __restrict__ A, const float* __restrict__ W3,
                                                  const float* __restrict__ dinv, float* __restrict__ H3) {
    __shared__ float w3s[256];
    w3s[threadIdx.x] = W3[threadIdx.x];
    __syncthreads();
    int n = blockIdx.x * 256 + threadIdx.x;
    if (n >= NN) return;
    const float4* ar = (const float4*)(A + (size_t)n * CH);
    float a0 = 0.f, a1 = 0.f;
#pragma unroll
    for (int k4 = 0; k4 < 32; ++k4) {
        float4 a = ar[k4];
        int k = k4 * 4;
        a0 += a.x * w3s[(k + 0) * 2] + a.y * w3s[(k + 1) * 2] + a.z * w3s[(k + 2) * 2] + a.w * w3s[(k + 3) * 2];
        a1 += a.x * w3s[(k + 0) * 2 + 1] + a.y * w3s[(k + 1) * 2 + 1] + a.z * w3s[(k + 2) * 2 + 1] + a.w * w3s[(k + 3) * 2 + 1];
    }
    float dv = dinv[n];
    *(float2*)(H3 + (size_t)n * 2) = make_float2(a0 * dv, a1 * dv);
}

__global__ __launch_bounds__(256) void k_agg_out(const float* __restrict__ H3, const int* __restrict__ rp,
                                                 const int* __restrict__ col, const float* __restrict__ dinv,
                                                 const float* __restrict__ b3, float* __restrict__ out) {
    int n = blockIdx.x * 256 + threadIdx.x;
    if (n >= NN) return;
    int beg = rp[n], end = rp[n + 1];
    float a0 = 0.f, a1 = 0.f;
    for (int e = beg; e < end; ++e) {
        int s = col[e];
        float2 hv = *(const float2*)(H3 + (size_t)s * 2);
        a0 += hv.x;
        a1 += hv.y;
    }
    float dv = dinv[n];
    out[(size_t)n * 2 + 0] = fmaf(a0, dv, b3[0]);
    out[(size_t)n * 2 + 1] = fmaf(a1, dv, b3[1]);
}

// ---------------- launch ----------------

extern "C" void kernel_launch(void* const* d_in, const int* in_sizes, int n_in,
                              void* d_out, int out_size, void* d_ws, size_t ws_size,
                              hipStream_t stream) {
    const float* x  = (const float*)d_in[0];
    const int* ei   = (const int*)d_in[1];
    const int* src  = ei;
    const int* dst  = ei + EE;
    const float* W1 = (const float*)d_in[2];
    const float* b1 = (const float*)d_in[3];
    const float* g1 = (const float*)d_in[4];
    const float* be1 = (const float*)d_in[5];
    const float* rm1 = (const float*)d_in[6];
    const float* rv1 = (const float*)d_in[7];
    const float* W2 = (const float*)d_in[8];
    const float* b2 = (const float*)d_in[9];
    const float* g2 = (const float*)d_in[10];
    const float* be2 = (const float*)d_in[11];
    const float* rm2 = (const float*)d_in[12];
    const float* rv2 = (const float*)d_in[13];
    const float* W3 = (const float*)d_in[14];
    const float* b3 = (const float*)d_in[15];
    float* out = (float*)d_out;

    char* p = (char*)d_ws;
    auto carve = [&](size_t bytes) -> void* {
        void* r = (void*)p;
        p += (bytes + 255) & ~(size_t)255;
        return r;
    };
    int* cnt    = (int*)carve((size_t)NN * 4);
    int* rp     = (int*)carve((size_t)(NN + 1) * 4);
    int* cur    = (int*)carve((size_t)NN * 4);
    float* dinv = (float*)carve((size_t)NN * 4);
    int* col    = (int*)carve((size_t)(EE + NN) * 4);
    int* bsum   = (int*)carve(1024 * 4);
    float* sc1  = (float*)carve(128 * 4);
    float* sh1  = (float*)carve(128 * 4);
    float* sc2  = (float*)carve(128 * 4);
    float* sh2  = (float*)carve(128 * 4);
    float* bufA = (float*)carve((size_t)NN * CH * 4);
    float* bufB = (float*)carve((size_t)NN * CH * 4);
    float* h3   = (float*)carve((size_t)NN * 2 * 4);

    hipMemsetAsync(cnt, 0, (size_t)NN * 4, stream);
    hipMemsetAsync(cur, 0, (size_t)NN * 4, stream);

    int nb = (NN + 1023) / 1024;
    k_count<<<EE / 256, 256, 0, stream>>>(dst, cnt);
    k_scan1<<<nb, 256, 0, stream>>>(cnt, rp, bsum);
    k_scan2<<<1, 256, 0, stream>>>(bsum, nb);
    k_scan3<<<(NN + 256) / 256, 256, 0, stream>>>(rp, bsum, cnt, dinv);
    k_fill<<<(EE + NN + 255) / 256, 256, 0, stream>>>(src, dst, rp, cur, col);
    k_bn<<<1, 128, 0, stream>>>(b1, g1, be1, rm1, rv1, sc1, sh1);
    k_bn<<<1, 128, 0, stream>>>(b2, g2, be2, rm2, rv2, sc2, sh2);

    k_gemm128<<<(NN + 63) / 64, 256, 0, stream>>>(x, W1, dinv, bufA, NN);
    k_agg128<<<(NN + 3) / 4, 256, 0, stream>>>(bufA, rp, col, dinv, sc1, sh1, bufB);
    k_gemm128<<<(NN + 63) / 64, 256, 0, stream>>>(bufB, W2, dinv, bufA, NN);
    k_agg128<<<(NN + 3) / 4, 256, 0, stream>>>(bufA, rp, col, dinv, sc2, sh2, bufB);
    k_gemm_out<<<(NN + 255) / 256, 256, 0, stream>>>(bufB, W3, dinv, h3);
    k_agg_out<<<(NN + 255) / 256, 256, 0, stream>>>(h3, rp, col, dinv, b3, out);
}

// Round 2
// 435.863 us; speedup vs baseline: 1.3267x; 1.3267x over previous
//
#include <hip/hip_runtime.h>

#define NN 100000
#define EE 1600000
#define CH 128

// bucketed CSR build params
#define S_NODES 512
#define NBUCK 196        // ceil(NN / 512)
#define CAP_E 10240      // per-bucket edge capacity (mean 8192, std ~90 -> >20 sigma margin)

// ---------------- CSR build: bucketed two-phase (no random global scatter) ----------------

// Pass A: partition edges into dst-buckets. Packed entry = (src<<9) | (dst & 511).
__global__ __launch_bounds__(256) void k_passA(const int* __restrict__ src, const int* __restrict__ dst,
                                               int* __restrict__ gcur, int* __restrict__ eb) {
    __shared__ int hist[NBUCK];
    __shared__ int curL[NBUCK];
    for (int t = threadIdx.x; t < NBUCK; t += 256) hist[t] = 0;
    __syncthreads();
    int base = blockIdx.x * 4096;
    int pk[16], bk[16];
#pragma unroll
    for (int j = 0; j < 16; ++j) {
        int i = base + threadIdx.x + 256 * j;
        if (i < EE) {
            int s = src[i], d = dst[i];
            bk[j] = d >> 9;
            pk[j] = (s << 9) | (d & 511);
            atomicAdd(&hist[bk[j]], 1);
        } else bk[j] = -1;
    }
    __syncthreads();
    for (int t = threadIdx.x; t < NBUCK; t += 256) {
        int h = hist[t];
        curL[t] = (h > 0) ? atomicAdd(&gcur[t], h) : 0;
    }
    __syncthreads();
#pragma unroll
    for (int j = 0; j < 16; ++j) {
        if (bk[j] >= 0) {
            int pos = atomicAdd(&curL[bk[j]], 1);
            if (pos < CAP_E) eb[bk[j] * CAP_E + pos] = pk[j];
        }
    }
}

// Pass B1: per-node edge counts from bucket data (LDS atomics only).
__global__ __launch_bounds__(256) void k_passB1(const int* __restrict__ gcur, const int* __restrict__ eb,
                                                int* __restrict__ cnt) {
    __shared__ int c[S_NODES];
    int bId = blockIdx.x;
    for (int t = threadIdx.x; t < S_NODES; t += 256) c[t] = 0;
    __syncthreads();
    int n = min(gcur[bId], CAP_E);
    const int* e = eb + (size_t)bId * CAP_E;
    for (int i = threadIdx.x; i < n; i += 256) atomicAdd(&c[e[i] & 511], 1);
    __syncthreads();
    for (int t = threadIdx.x; t < S_NODES; t += 256) {
        int node = bId * S_NODES + t;
        if (node < NN) cnt[node] = c[t];
    }
}

// Pass B2: place bucket's CSR segment in LDS, dump coalesced. Self-loop = last slot of each segment.
__global__ __launch_bounds__(256) void k_passB2(const int* __restrict__ gcur, const int* __restrict__ eb,
                                                const int* __restrict__ rp, int* __restrict__ col) {
    __shared__ int start[S_NODES + 1];
    __shared__ int cur[S_NODES];
    __shared__ int stage[CAP_E + S_NODES];
    int bId = blockIdx.x;
    int nbase = bId * S_NODES;
    for (int t = threadIdx.x; t <= S_NODES; t += 256) {
        int node = nbase + t;
        start[t] = rp[node < NN ? node : NN];
    }
    __syncthreads();
    int base = start[0];
    for (int t = threadIdx.x; t < S_NODES; t += 256) cur[t] = start[t] - base;
    __syncthreads();
    int n = min(gcur[bId], CAP_E);
    const int* e = eb + (size_t)bId * CAP_E;
    for (int i = threadIdx.x; i < n; i += 256) {
        int pe = e[i];
        int pos = atomicAdd(&cur[pe & 511], 1);
        stage[pos] = pe >> 9;
    }
    for (int t = threadIdx.x; t < S_NODES; t += 256) {
        int node = nbase + t;
        if (node < NN) stage[start[t + 1] - 1 - base] = node;  // self loop
    }
    __syncthreads();
    int total = start[S_NODES] - base;
    for (int i = threadIdx.x; i < total; i += 256) col[base + i] = stage[i];
}

// ---------------- scan (unchanged): rp = exclusive scan of (cnt[i]+1) ----------------

__global__ __launch_bounds__(256) void k_scan1(const int* __restrict__ cnt, int* __restrict__ rp,
                                               int* __restrict__ bsum) {
    __shared__ int ts[256];
    int tid = threadIdx.x;
    int base = blockIdx.x * 1024 + tid * 4;
    int v[4]; int s = 0;
#pragma unroll
    for (int j = 0; j < 4; ++j) { int i = base + j; v[j] = s; s += (i < NN) ? (cnt[i] + 1) : 0; }
    ts[tid] = s; __syncthreads();
    for (int off = 1; off < 256; off <<= 1) {
        int t = (tid >= off) ? ts[tid - off] : 0;
        __syncthreads();
        ts[tid] += t;
        __syncthreads();
    }
    int excl = ts[tid] - s;
#pragma unroll
    for (int j = 0; j < 4; ++j) { int i = base + j; if (i < NN) rp[i] = excl + v[j]; }
    if (tid == 255) bsum[blockIdx.x] = ts[255];
}

__global__ __launch_bounds__(256) void k_scan2(int* __restrict__ bsum, int nb) {
    __shared__ int ts[256];
    int tid = threadIdx.x;
    int v = (tid < nb) ? bsum[tid] : 0;
    ts[tid] = v; __syncthreads();
    for (int off = 1; off < 256; off <<= 1) {
        int t = (tid >= off) ? ts[tid - off] : 0;
        __syncthreads();
        ts[tid] += t;
        __syncthreads();
    }
    if (tid < nb) bsum[tid] = ts[tid] - v;
}

__global__ __launch_bounds__(256) void k_scan3(int* __restrict__ rp, const int* __restrict__ bsum,
                                               const int* __restrict__ cnt, float* __restrict__ dinv) {
    int i = blockIdx.x * 256 + threadIdx.x;
    if (i < NN) {
        rp[i] += bsum[i >> 10];
        dinv[i] = rsqrtf((float)(cnt[i] + 1));
    }
    if (i == NN) rp[NN] = EE + NN;
}

// ---------------- BN fold ----------------

__global__ __launch_bounds__(128) void k_bn(const float* __restrict__ b, const float* __restrict__ g,
                                            const float* __restrict__ be, const float* __restrict__ rm,
                                            const float* __restrict__ rv, float* __restrict__ sc,
                                            float* __restrict__ sh) {
    int t = threadIdx.x;
    float s = g[t] * rsqrtf(rv[t] + 1e-5f);
    sc[t] = s;
    sh[t] = (b[t] - rm[t]) * s + be[t];
}

// ---------------- GEMM [N,128]@[128,128], epilogue: row *= dinv[row] ----------------

__global__ __launch_bounds__(256) void k_gemm128(const float* __restrict__ A, const float* __restrict__ W,
                                                 const float* __restrict__ dinv, float* __restrict__ C,
                                                 int nrows) {
    __shared__ float Ws[CH * CH];
    {
        const float4* wv = (const float4*)W;
        float4* sv = (float4*)Ws;
#pragma unroll
        for (int i = 0; i < 16; ++i) sv[threadIdx.x + 256 * i] = wv[threadIdx.x + 256 * i];
    }
    __syncthreads();
    int tx = threadIdx.x & 15, ty = threadIdx.x >> 4;
    int row0 = blockIdx.x * 64 + ty * 4, col0 = tx * 8;
    int r[4];
#pragma unroll
    for (int j = 0; j < 4; ++j) { int rr = row0 + j; r[j] = (rr < nrows) ? rr : (nrows - 1); }
    float acc[4][8] = {};
    for (int k4 = 0; k4 < 32; ++k4) {
        float4 a4[4];
#pragma unroll
        for (int j = 0; j < 4; ++j) a4[j] = *(const float4*)(A + (size_t)r[j] * CH + k4 * 4);
#pragma unroll
        for (int kk = 0; kk < 4; ++kk) {
            const float4 w0 = *(const float4*)(Ws + (k4 * 4 + kk) * CH + col0);
            const float4 w1 = *(const float4*)(Ws + (k4 * 4 + kk) * CH + col0 + 4);
#pragma unroll
            for (int j = 0; j < 4; ++j) {
                float av = (&a4[j].x)[kk];
                acc[j][0] += av * w0.x; acc[j][1] += av * w0.y;
                acc[j][2] += av * w0.z; acc[j][3] += av * w0.w;
                acc[j][4] += av * w1.x; acc[j][5] += av * w1.y;
                acc[j][6] += av * w1.z; acc[j][7] += av * w1.w;
            }
        }
    }
#pragma unroll
    for (int j = 0; j < 4; ++j) {
        int rr = row0 + j;
        if (rr < nrows) {
            float dv = dinv[rr];
            float4 o0 = make_float4(acc[j][0] * dv, acc[j][1] * dv, acc[j][2] * dv, acc[j][3] * dv);
            float4 o1 = make_float4(acc[j][4] * dv, acc[j][5] * dv, acc[j][6] * dv, acc[j][7] * dv);
            *(float4*)(C + (size_t)rr * CH + col0) = o0;
            *(float4*)(C + (size_t)rr * CH + col0 + 4) = o1;
        }
    }
}

// ---------------- Aggregation, 128ch ----------------

__global__ __launch_bounds__(256) void k_agg128(const float* __restrict__ h, const int* __restrict__ rp,
                                                const int* __restrict__ col, const float* __restrict__ dinv,
                                                const float* __restrict__ sc, const float* __restrict__ sh,
                                                float* __restrict__ out) {
    int node = blockIdx.x * 4 + (threadIdx.x >> 6);
    if (node >= NN) return;
    node = __builtin_amdgcn_readfirstlane(node);
    int lane = threadIdx.x & 63;
    int beg = rp[node], end = rp[node + 1];
    float2 acc = make_float2(0.f, 0.f);
    int e = beg;
    for (; e + 2 <= end; e += 2) {
        int s0 = col[e], s1 = col[e + 1];
        const float2 h0 = *(const float2*)(h + (size_t)s0 * CH + lane * 2);
        const float2 h1 = *(const float2*)(h + (size_t)s1 * CH + lane * 2);
        acc.x += h0.x + h1.x;
        acc.y += h0.y + h1.y;
    }
    if (e < end) {
        int s0 = col[e];
        const float2 h0 = *(const float2*)(h + (size_t)s0 * CH + lane * 2);
        acc.x += h0.x;
        acc.y += h0.y;
    }
    float dv = dinv[node];
    int c = lane * 2;
    float2 scv = *(const float2*)(sc + c);
    float2 shv = *(const float2*)(sh + c);
    float o0 = fmaxf(fmaf(acc.x * dv, scv.x, shv.x), 0.f);
    float o1 = fmaxf(fmaf(acc.y * dv, scv.y, shv.y), 0.f);
    *(float2*)(out + (size_t)node * CH + c) = make_float2(o0, o1);
}

// ---------------- Layer 3 ----------------

__global__ __launch_bounds__(256) void k_gemm_out(const float* __restrict__ A, const float* __restrict__ W3,
                                                  const float* __restrict__ dinv, float* __restrict__ H3) {
    __shared__ float w3s[256];
    w3s[threadIdx.x] = W3[threadIdx.x];
    __syncthreads();
    int n = blockIdx.x * 256 + threadIdx.x;
    if (n >= NN) return;
    const float4* ar = (const float4*)(A + (size_t)n * CH);
    float a0 = 0.f, a1 = 0.f;
#pragma unroll
    for (int k4 = 0; k4 < 32; ++k4) {
        float4 a = ar[k4];
        int k = k4 * 4;
        a0 += a.x * w3s[(k + 0) * 2] + a.y * w3s[(k + 1) * 2] + a.z * w3s[(k + 2) * 2] + a.w * w3s[(k + 3) * 2];
        a1 += a.x * w3s[(k + 0) * 2 + 1] + a.y * w3s[(k + 1) * 2 + 1] + a.z * w3s[(k + 2) * 2 + 1] + a.w * w3s[(k + 3) * 2 + 1];
    }
    float dv = dinv[n];
    *(float2*)(H3 + (size_t)n * 2) = make_float2(a0 * dv, a1 * dv);
}

__global__ __launch_bounds__(256) void k_agg_out(const float* __restrict__ H3, const int* __restrict__ rp,
                                                 const int* __restrict__ col, const float* __restrict__ dinv,
                                                 const float* __restrict__ b3, float* __restrict__ out) {
    int n = blockIdx.x * 256 + threadIdx.x;
    if (n >= NN) return;
    int beg = rp[n], end = rp[n + 1];
    float a0 = 0.f, a1 = 0.f;
    for (int e = beg; e < end; ++e) {
        int s = col[e];
        float2 hv = *(const float2*)(H3 + (size_t)s * 2);
        a0 += hv.x;
        a1 += hv.y;
    }
    float dv = dinv[n];
    out[(size_t)n * 2 + 0] = fmaf(a0, dv, b3[0]);
    out[(size_t)n * 2 + 1] = fmaf(a1, dv, b3[1]);
}

// ---------------- launch ----------------

extern "C" void kernel_launch(void* const* d_in, const int* in_sizes, int n_in,
                              void* d_out, int out_size, void* d_ws, size_t ws_size,
                              hipStream_t stream) {
    const float* x  = (const float*)d_in[0];
    const int* ei   = (const int*)d_in[1];
    const int* src  = ei;
    const int* dst  = ei + EE;
    const float* W1 = (const float*)d_in[2];
    const float* b1 = (const float*)d_in[3];
    const float* g1 = (const float*)d_in[4];
    const float* be1 = (const float*)d_in[5];
    const float* rm1 = (const float*)d_in[6];
    const float* rv1 = (const float*)d_in[7];
    const float* W2 = (const float*)d_in[8];
    const float* b2 = (const float*)d_in[9];
    const float* g2 = (const float*)d_in[10];
    const float* be2 = (const float*)d_in[11];
    const float* rm2 = (const float*)d_in[12];
    const float* rv2 = (const float*)d_in[13];
    const float* W3 = (const float*)d_in[14];
    const float* b3 = (const float*)d_in[15];
    float* out = (float*)d_out;

    char* p = (char*)d_ws;
    auto carve = [&](size_t bytes) -> void* {
        void* r = (void*)p;
        p += (bytes + 255) & ~(size_t)255;
        return r;
    };
    int* cnt    = (int*)carve((size_t)NN * 4);
    int* rp     = (int*)carve((size_t)(NN + 1) * 4);
    float* dinv = (float*)carve((size_t)NN * 4);
    int* col    = (int*)carve((size_t)(EE + NN) * 4);
    int* bsum   = (int*)carve(1024 * 4);
    float* sc1  = (float*)carve(128 * 4);
    float* sh1  = (float*)carve(128 * 4);
    float* sc2  = (float*)carve(128 * 4);
    float* sh2  = (float*)carve(128 * 4);
    float* bufA = (float*)carve((size_t)NN * CH * 4);
    float* bufB = (float*)carve((size_t)NN * CH * 4);
    float* h3   = (float*)carve((size_t)NN * 2 * 4);

    // bucket workspace aliases bufA (dead until first GEMM)
    int* eb   = (int*)bufA;                         // NBUCK*CAP_E ints = 8 MB < 51.2 MB
    int* gcur = eb + (size_t)NBUCK * CAP_E;         // NBUCK ints

    hipMemsetAsync(gcur, 0, (size_t)NBUCK * 4, stream);

    int nb = (NN + 1023) / 1024;
    k_passA<<<(EE + 4095) / 4096, 256, 0, stream>>>(src, dst, gcur, eb);
    k_passB1<<<NBUCK, 256, 0, stream>>>(gcur, eb, cnt);
    k_scan1<<<nb, 256, 0, stream>>>(cnt, rp, bsum);
    k_scan2<<<1, 256, 0, stream>>>(bsum, nb);
    k_scan3<<<(NN + 256) / 256, 256, 0, stream>>>(rp, bsum, cnt, dinv);
    k_passB2<<<NBUCK, 256, 0, stream>>>(gcur, eb, rp, col);
    k_bn<<<1, 128, 0, stream>>>(b1, g1, be1, rm1, rv1, sc1, sh1);
    k_bn<<<1, 128, 0, stream>>>(b2, g2, be2, rm2, rv2, sc2, sh2);

    k_gemm128<<<(NN + 63) / 64, 256, 0, stream>>>(x, W1, dinv, bufA, NN);
    k_agg128<<<(NN + 3) / 4, 256, 0, stream>>>(bufA, rp, col, dinv, sc1, sh1, bufB);
    k_gemm128<<<(NN + 63) / 64, 256, 0, stream>>>(bufB, W2, dinv, bufA, NN);
    k_agg128<<<(NN + 3) / 4, 256, 0, stream>>>(bufA, rp, col, dinv, sc2, sh2, bufB);
    k_gemm_out<<<(NN + 255) / 256, 256, 0, stream>>>(bufB, W3, dinv, h3);
    k_agg_out<<<(NN + 255) / 256, 256, 0, stream>>>(h3, rp, col, dinv, b3, out);
}

// Round 3
// 250.864 us; speedup vs baseline: 2.3051x; 1.7374x over previous
//
#include <hip/hip_runtime.h>

#define NN 100000
#define EE 1600000
#define CH 128

typedef _Float16 h2 __attribute__((ext_vector_type(2)));
typedef _Float16 h8 __attribute__((ext_vector_type(8)));
typedef float f32x4 __attribute__((ext_vector_type(4)));

// bucketed CSR build params
#define S_NODES 512
#define NBUCK 196
#define CAP_E 10240

// ---------------- CSR build: bucketed two-phase ----------------

__global__ __launch_bounds__(256) void k_passA(const int* __restrict__ src, const int* __restrict__ dst,
                                               int* __restrict__ gcur, int* __restrict__ eb) {
    __shared__ int hist[NBUCK];
    __shared__ int curL[NBUCK];
    for (int t = threadIdx.x; t < NBUCK; t += 256) hist[t] = 0;
    __syncthreads();
    int base = blockIdx.x * 4096;
    int pk[16], bk[16];
#pragma unroll
    for (int j = 0; j < 16; ++j) {
        int i = base + threadIdx.x + 256 * j;
        if (i < EE) {
            int s = src[i], d = dst[i];
            bk[j] = d >> 9;
            pk[j] = (s << 9) | (d & 511);
            atomicAdd(&hist[bk[j]], 1);
        } else bk[j] = -1;
    }
    __syncthreads();
    for (int t = threadIdx.x; t < NBUCK; t += 256) {
        int h = hist[t];
        curL[t] = (h > 0) ? atomicAdd(&gcur[t], h) : 0;
    }
    __syncthreads();
#pragma unroll
    for (int j = 0; j < 16; ++j) {
        if (bk[j] >= 0) {
            int pos = atomicAdd(&curL[bk[j]], 1);
            if (pos < CAP_E) eb[bk[j] * CAP_E + pos] = pk[j];
        }
    }
}

__global__ __launch_bounds__(256) void k_passB1(const int* __restrict__ gcur, const int* __restrict__ eb,
                                                int* __restrict__ cnt) {
    __shared__ int c[S_NODES];
    int bId = blockIdx.x;
    for (int t = threadIdx.x; t < S_NODES; t += 256) c[t] = 0;
    __syncthreads();
    int n = min(gcur[bId], CAP_E);
    const int* e = eb + (size_t)bId * CAP_E;
    for (int i = threadIdx.x; i < n; i += 256) atomicAdd(&c[e[i] & 511], 1);
    __syncthreads();
    for (int t = threadIdx.x; t < S_NODES; t += 256) {
        int node = bId * S_NODES + t;
        if (node < NN) cnt[node] = c[t];
    }
}

__global__ __launch_bounds__(256) void k_passB2(const int* __restrict__ gcur, const int* __restrict__ eb,
                                                const int* __restrict__ rp, int* __restrict__ col) {
    __shared__ int start[S_NODES + 1];
    __shared__ int cur[S_NODES];
    __shared__ int stage[CAP_E + S_NODES];
    int bId = blockIdx.x;
    int nbase = bId * S_NODES;
    for (int t = threadIdx.x; t <= S_NODES; t += 256) {
        int node = nbase + t;
        start[t] = rp[node < NN ? node : NN];
    }
    __syncthreads();
    int base = start[0];
    for (int t = threadIdx.x; t < S_NODES; t += 256) cur[t] = start[t] - base;
    __syncthreads();
    int n = min(gcur[bId], CAP_E);
    const int* e = eb + (size_t)bId * CAP_E;
    for (int i = threadIdx.x; i < n; i += 256) {
        int pe = e[i];
        int pos = atomicAdd(&cur[pe & 511], 1);
        stage[pos] = pe >> 9;
    }
    for (int t = threadIdx.x; t < S_NODES; t += 256) {
        int node = nbase + t;
        if (node < NN) stage[start[t + 1] - 1 - base] = node;
    }
    __syncthreads();
    int total = start[S_NODES] - base;
    for (int i = threadIdx.x; i < total; i += 256) col[base + i] = stage[i];
}

// ---------------- scans ----------------

__global__ __launch_bounds__(256) void k_scan1(const int* __restrict__ cnt, int* __restrict__ rp,
                                               int* __restrict__ bsum) {
    __shared__ int ts[256];
    int tid = threadIdx.x;
    int base = blockIdx.x * 1024 + tid * 4;
    int v[4]; int s = 0;
#pragma unroll
    for (int j = 0; j < 4; ++j) { int i = base + j; v[j] = s; s += (i < NN) ? (cnt[i] + 1) : 0; }
    ts[tid] = s; __syncthreads();
    for (int off = 1; off < 256; off <<= 1) {
        int t = (tid >= off) ? ts[tid - off] : 0;
        __syncthreads();
        ts[tid] += t;
        __syncthreads();
    }
    int excl = ts[tid] - s;
#pragma unroll
    for (int j = 0; j < 4; ++j) { int i = base + j; if (i < NN) rp[i] = excl + v[j]; }
    if (tid == 255) bsum[blockIdx.x] = ts[255];
}

__global__ __launch_bounds__(256) void k_scan2(int* __restrict__ bsum, int nb) {
    __shared__ int ts[256];
    int tid = threadIdx.x;
    int v = (tid < nb) ? bsum[tid] : 0;
    ts[tid] = v; __syncthreads();
    for (int off = 1; off < 256; off <<= 1) {
        int t = (tid >= off) ? ts[tid - off] : 0;
        __syncthreads();
        ts[tid] += t;
        __syncthreads();
    }
    if (tid < nb) bsum[tid] = ts[tid] - v;
}

__global__ __launch_bounds__(256) void k_scan3(int* __restrict__ rp, const int* __restrict__ bsum,
                                               const int* __restrict__ cnt, float* __restrict__ dinv) {
    int i = blockIdx.x * 256 + threadIdx.x;
    if (i < NN) {
        rp[i] += bsum[i >> 10];
        dinv[i] = rsqrtf((float)(cnt[i] + 1));
    }
    if (i == NN) rp[NN] = EE + NN;
}

// ---------------- BN fold ----------------

__global__ __launch_bounds__(128) void k_bn(const float* __restrict__ b, const float* __restrict__ g,
                                            const float* __restrict__ be, const float* __restrict__ rm,
                                            const float* __restrict__ rv, float* __restrict__ sc,
                                            float* __restrict__ sh) {
    int t = threadIdx.x;
    float s = g[t] * rsqrtf(rv[t] + 1e-5f);
    sc[t] = s;
    sh[t] = (b[t] - rm[t]) * s + be[t];
}

// ---------------- prep: x -> fp16; W -> fp16 transposed ----------------

__global__ __launch_bounds__(256) void k_cvt(const float* __restrict__ x, _Float16* __restrict__ xh) {
    int i = blockIdx.x * 256 + threadIdx.x;
    const float4* xv = (const float4*)x + (size_t)i * 2;
    float4 a = xv[0], b = xv[1];
    h8 o;
    o[0] = (_Float16)a.x; o[1] = (_Float16)a.y; o[2] = (_Float16)a.z; o[3] = (_Float16)a.w;
    o[4] = (_Float16)b.x; o[5] = (_Float16)b.y; o[6] = (_Float16)b.z; o[7] = (_Float16)b.w;
    *(h8*)(xh + (size_t)i * 8) = o;
}

__global__ __launch_bounds__(128) void k_prep_w(const float* __restrict__ W, _Float16* __restrict__ Wt) {
    int n = blockIdx.x, k = threadIdx.x;
    Wt[n * 128 + k] = (_Float16)W[k * 128 + n];
}

// ---------------- MFMA GEMM [N,128]@[128,128] fp16, epilogue row*=dinv, out fp16 ----------------
// A-frag: lane holds A[row0 + (l&15)][ks*32 + (l>>4)*8 + j]  (16B contiguous, from global)
// B-frag: lane holds W[k][c*16+(l&15)] = Wt[c*16+(l&15)][k]  (from LDS, XOR-swizzled 16B slots)
// D: lane holds D[(l>>4)*4 + j][l&15] per 16x16 tile

__global__ __launch_bounds__(256) void k_gemm_mfma(const _Float16* __restrict__ A,
                                                   const _Float16* __restrict__ Wt,
                                                   const float* __restrict__ dinv,
                                                   _Float16* __restrict__ C) {
    __shared__ _Float16 Wl[CH * CH];  // 32 KB, [row][16B-slot swizzled]
    {
        const float4* wg = (const float4*)Wt;
#pragma unroll
        for (int i = 0; i < 8; ++i) {
            int chunk = i * 256 + threadIdx.x;      // 2048 x 16B
            int row = chunk >> 4, slot = chunk & 15;
            float4 v = wg[chunk];
            *(float4*)((char*)Wl + row * 256 + ((slot ^ (row & 15)) * 16)) = v;
        }
    }
    __syncthreads();
    int lane = threadIdx.x & 63;
    int l15 = lane & 15, lhi = lane >> 4;
    int row0 = blockIdx.x * 64 + (threadIdx.x >> 6) * 16;
    if (row0 >= NN) return;   // NN % 16 == 0, no partial tiles

    h8 afrag[4];
    const _Float16* Arow = A + (size_t)(row0 + l15) * CH + lhi * 8;
#pragma unroll
    for (int ks = 0; ks < 4; ++ks) afrag[ks] = *(const h8*)(Arow + ks * 32);

    f32x4 acc[8] = {};
#pragma unroll
    for (int ks = 0; ks < 4; ++ks) {
        int slot = ks * 4 + lhi;
#pragma unroll
        for (int c = 0; c < 8; ++c) {
            int brow = c * 16 + l15;
            h8 b = *(const h8*)((char*)Wl + brow * 256 + ((slot ^ (brow & 15)) * 16));
            acc[c] = __builtin_amdgcn_mfma_f32_16x16x32_f16(afrag[ks], b, acc[c], 0, 0, 0);
        }
    }
    float dv[4];
#pragma unroll
    for (int j = 0; j < 4; ++j) dv[j] = dinv[row0 + lhi * 4 + j];
#pragma unroll
    for (int c = 0; c < 8; ++c)
#pragma unroll
        for (int j = 0; j < 4; ++j) {
            float v = acc[c][j] * dv[j];
            C[(size_t)(row0 + lhi * 4 + j) * CH + c * 16 + l15] = (_Float16)v;
        }
}

// ---------------- Aggregation, fp16 rows, fused dinv+BN+ReLU, fp16 out ----------------

__global__ __launch_bounds__(256) void k_agg128h(const _Float16* __restrict__ h, const int* __restrict__ rp,
                                                 const int* __restrict__ col, const float* __restrict__ dinv,
                                                 const float* __restrict__ sc, const float* __restrict__ sh,
                                                 _Float16* __restrict__ out) {
    int node = blockIdx.x * 4 + (threadIdx.x >> 6);
    if (node >= NN) return;
    node = __builtin_amdgcn_readfirstlane(node);
    int lane = threadIdx.x & 63;
    int beg = rp[node], end = rp[node + 1];
    float ax = 0.f, ay = 0.f;
    int e = beg;
    for (; e + 4 <= end; e += 4) {
        int s0 = col[e], s1 = col[e + 1], s2 = col[e + 2], s3 = col[e + 3];
        h2 v0 = *(const h2*)(h + (size_t)s0 * CH + lane * 2);
        h2 v1 = *(const h2*)(h + (size_t)s1 * CH + lane * 2);
        h2 v2 = *(const h2*)(h + (size_t)s2 * CH + lane * 2);
        h2 v3 = *(const h2*)(h + (size_t)s3 * CH + lane * 2);
        ax += (float)v0[0] + (float)v1[0] + (float)v2[0] + (float)v3[0];
        ay += (float)v0[1] + (float)v1[1] + (float)v2[1] + (float)v3[1];
    }
    for (; e < end; ++e) {
        int s0 = col[e];
        h2 v0 = *(const h2*)(h + (size_t)s0 * CH + lane * 2);
        ax += (float)v0[0];
        ay += (float)v0[1];
    }
    float dvn = dinv[node];
    int c = lane * 2;
    float2 scv = *(const float2*)(sc + c);
    float2 shv = *(const float2*)(sh + c);
    float o0 = fmaxf(fmaf(ax * dvn, scv.x, shv.x), 0.f);
    float o1 = fmaxf(fmaf(ay * dvn, scv.y, shv.y), 0.f);
    h2 o; o[0] = (_Float16)o0; o[1] = (_Float16)o1;
    *(h2*)(out + (size_t)node * CH + c) = o;
}

// ---------------- Layer 3 ----------------

__global__ __launch_bounds__(256) void k_gemm_out(const _Float16* __restrict__ A, const float* __restrict__ W3,
                                                  const float* __restrict__ dinv, float* __restrict__ H3) {
    __shared__ float w3s[256];
    w3s[threadIdx.x] = W3[threadIdx.x];
    __syncthreads();
    int n = blockIdx.x * 256 + threadIdx.x;
    if (n >= NN) return;
    const h8* ar = (const h8*)(A + (size_t)n * CH);
    float a0 = 0.f, a1 = 0.f;
#pragma unroll
    for (int kb = 0; kb < 16; ++kb) {
        h8 a = ar[kb];
#pragma unroll
        for (int j = 0; j < 8; ++j) {
            float av = (float)a[j];
            int k = kb * 8 + j;
            a0 += av * w3s[k * 2];
            a1 += av * w3s[k * 2 + 1];
        }
    }
    float dv = dinv[n];
    *(float2*)(H3 + (size_t)n * 2) = make_float2(a0 * dv, a1 * dv);
}

__global__ __launch_bounds__(256) void k_agg_out(const float* __restrict__ H3, const int* __restrict__ rp,
                                                 const int* __restrict__ col, const float* __restrict__ dinv,
                                                 const float* __restrict__ b3, float* __restrict__ out) {
    int n = blockIdx.x * 256 + threadIdx.x;
    if (n >= NN) return;
    int beg = rp[n], end = rp[n + 1];
    float a0 = 0.f, a1 = 0.f;
    for (int e = beg; e < end; ++e) {
        int s = col[e];
        float2 hv = *(const float2*)(H3 + (size_t)s * 2);
        a0 += hv.x;
        a1 += hv.y;
    }
    float dv = dinv[n];
    out[(size_t)n * 2 + 0] = fmaf(a0, dv, b3[0]);
    out[(size_t)n * 2 + 1] = fmaf(a1, dv, b3[1]);
}

// ---------------- launch ----------------

extern "C" void kernel_launch(void* const* d_in, const int* in_sizes, int n_in,
                              void* d_out, int out_size, void* d_ws, size_t ws_size,
                              hipStream_t stream) {
    const float* x  = (const float*)d_in[0];
    const int* ei   = (const int*)d_in[1];
    const int* src  = ei;
    const int* dst  = ei + EE;
    const float* W1 = (const float*)d_in[2];
    const float* b1 = (const float*)d_in[3];
    const float* g1 = (const float*)d_in[4];
    const float* be1 = (const float*)d_in[5];
    const float* rm1 = (const float*)d_in[6];
    const float* rv1 = (const float*)d_in[7];
    const float* W2 = (const float*)d_in[8];
    const float* b2 = (const float*)d_in[9];
    const float* g2 = (const float*)d_in[10];
    const float* be2 = (const float*)d_in[11];
    const float* rm2 = (const float*)d_in[12];
    const float* rv2 = (const float*)d_in[13];
    const float* W3 = (const float*)d_in[14];
    const float* b3 = (const float*)d_in[15];
    float* out = (float*)d_out;

    char* p = (char*)d_ws;
    auto carve = [&](size_t bytes) -> void* {
        void* r = (void*)p;
        p += (bytes + 255) & ~(size_t)255;
        return r;
    };
    int* cnt    = (int*)carve((size_t)NN * 4);
    int* rp     = (int*)carve((size_t)(NN + 1) * 4);
    float* dinv = (float*)carve((size_t)NN * 4);
    int* col    = (int*)carve((size_t)(EE + NN) * 4);
    int* bsum   = (int*)carve(1024 * 4);
    float* sc1  = (float*)carve(128 * 4);
    float* sh1  = (float*)carve(128 * 4);
    float* sc2  = (float*)carve(128 * 4);
    float* sh2  = (float*)carve(128 * 4);
    _Float16* bufA = (_Float16*)carve((size_t)NN * CH * 2);
    _Float16* bufB = (_Float16*)carve((size_t)NN * CH * 2);
    _Float16* xh   = (_Float16*)carve((size_t)NN * CH * 2);
    _Float16* Wt1  = (_Float16*)carve(128 * 128 * 2);
    _Float16* Wt2  = (_Float16*)carve(128 * 128 * 2);
    float* h3   = (float*)carve((size_t)NN * 2 * 4);

    // bucket workspace aliases bufA+bufB (dead until first GEMM): 8.03 MB < 51.2 MB
    int* eb   = (int*)bufA;
    int* gcur = eb + (size_t)NBUCK * CAP_E;

    hipMemsetAsync(gcur, 0, (size_t)NBUCK * 4, stream);

    int nb = (NN + 1023) / 1024;
    k_passA<<<(EE + 4095) / 4096, 256, 0, stream>>>(src, dst, gcur, eb);
    k_passB1<<<NBUCK, 256, 0, stream>>>(gcur, eb, cnt);
    k_scan1<<<nb, 256, 0, stream>>>(cnt, rp, bsum);
    k_scan2<<<1, 256, 0, stream>>>(bsum, nb);
    k_scan3<<<(NN + 256) / 256, 256, 0, stream>>>(rp, bsum, cnt, dinv);
    k_passB2<<<NBUCK, 256, 0, stream>>>(gcur, eb, rp, col);

    k_cvt<<<NN * CH / 8 / 256, 256, 0, stream>>>(x, xh);
    k_prep_w<<<128, 128, 0, stream>>>(W1, Wt1);
    k_prep_w<<<128, 128, 0, stream>>>(W2, Wt2);
    k_bn<<<1, 128, 0, stream>>>(b1, g1, be1, rm1, rv1, sc1, sh1);
    k_bn<<<1, 128, 0, stream>>>(b2, g2, be2, rm2, rv2, sc2, sh2);

    k_gemm_mfma<<<(NN + 63) / 64, 256, 0, stream>>>(xh, Wt1, dinv, bufA);
    k_agg128h<<<(NN + 3) / 4, 256, 0, stream>>>(bufA, rp, col, dinv, sc1, sh1, bufB);
    k_gemm_mfma<<<(NN + 63) / 64, 256, 0, stream>>>(bufB, Wt2, dinv, bufA);
    k_agg128h<<<(NN + 3) / 4, 256, 0, stream>>>(bufA, rp, col, dinv, sc2, sh2, bufB);
    k_gemm_out<<<(NN + 255) / 256, 256, 0, stream>>>(bufB, W3, dinv, h3);
    k_agg_out<<<(NN + 255) / 256, 256, 0, stream>>>(h3, rp, col, dinv, b3, out);
}

// Round 4
// 228.026 us; speedup vs baseline: 2.5359x; 1.1002x over previous
//
#include <hip/hip_runtime.h>

#define NN 100000
#define EE 1600000
#define CH 128

typedef _Float16 h2 __attribute__((ext_vector_type(2)));
typedef _Float16 h8 __attribute__((ext_vector_type(8)));
typedef float f32x4 __attribute__((ext_vector_type(4)));

// bucketed CSR build params
#define S_NODES 512
#define NBUCK 196
#define CAP_E 10240

// ---------------- Pass A: partition edges into dst-buckets ----------------
// Packed entry = (src<<9) | (dst & 511).

__global__ __launch_bounds__(256) void k_passA(const int* __restrict__ src, const int* __restrict__ dst,
                                               int* __restrict__ gcur, int* __restrict__ eb) {
    __shared__ int hist[NBUCK];
    __shared__ int curL[NBUCK];
    for (int t = threadIdx.x; t < NBUCK; t += 256) hist[t] = 0;
    __syncthreads();
    int base = blockIdx.x * 4096;
    int pk[16], bk[16];
#pragma unroll
    for (int j = 0; j < 16; ++j) {
        int i = base + threadIdx.x + 256 * j;
        if (i < EE) {
            int s = src[i], d = dst[i];
            bk[j] = d >> 9;
            pk[j] = (s << 9) | (d & 511);
            atomicAdd(&hist[bk[j]], 1);
        } else bk[j] = -1;
    }
    __syncthreads();
    for (int t = threadIdx.x; t < NBUCK; t += 256) {
        int h = hist[t];
        curL[t] = (h > 0) ? atomicAdd(&gcur[t], h) : 0;
    }
    __syncthreads();
#pragma unroll
    for (int j = 0; j < 16; ++j) {
        if (bk[j] >= 0) {
            int pos = atomicAdd(&curL[bk[j]], 1);
            if (pos < CAP_E) eb[bk[j] * CAP_E + pos] = pk[j];
        }
    }
}

// ---------------- bucket-base scan (196 totals) ----------------

__global__ __launch_bounds__(256) void k_bscan(const int* __restrict__ gcur, int* __restrict__ bbase,
                                               int* __restrict__ rp) {
    __shared__ int ts[256];
    int t = threadIdx.x;
    int nn = (t < NBUCK) ? min(S_NODES, NN - t * S_NODES) : 0;
    int v = (t < NBUCK) ? (min(gcur[t], CAP_E) + nn) : 0;
    ts[t] = v; __syncthreads();
    for (int off = 1; off < 256; off <<= 1) {
        int u = (t >= off) ? ts[t - off] : 0;
        __syncthreads();
        ts[t] += u;
        __syncthreads();
    }
    if (t < NBUCK) bbase[t] = ts[t] - v;
    if (t == 0) rp[NN] = EE + NN;
}

// ---------------- fused Pass B: count + local scan + rp/dinv + place + dump ----------------

__global__ __launch_bounds__(256) void k_passB(const int* __restrict__ gcur, const int* __restrict__ eb,
                                               const int* __restrict__ bbase, int* __restrict__ rp,
                                               float* __restrict__ dinv, int* __restrict__ col) {
    __shared__ int c[S_NODES];
    __shared__ int excl[S_NODES];
    __shared__ int cur[S_NODES];
    __shared__ int ts[256];
    __shared__ int stage[CAP_E + S_NODES];
    int bId = blockIdx.x;
    int nbase = bId * S_NODES;
    int tid = threadIdx.x;
    c[tid] = 0; c[tid + 256] = 0;
    __syncthreads();
    int n = min(gcur[bId], CAP_E);
    const int* e = eb + (size_t)bId * CAP_E;
    for (int i = tid; i < n; i += 256) atomicAdd(&c[e[i] & 511], 1);
    __syncthreads();
    // exclusive scan of slot sizes (c[t]+1 for valid nodes), 2 elems/thread
    int n0 = nbase + 2 * tid, n1 = n0 + 1;
    int v0 = (n0 < NN) ? c[2 * tid] + 1 : 0;
    int v1 = (n1 < NN) ? c[2 * tid + 1] + 1 : 0;
    int s = v0 + v1;
    ts[tid] = s; __syncthreads();
    for (int off = 1; off < 256; off <<= 1) {
        int u = (tid >= off) ? ts[tid - off] : 0;
        __syncthreads();
        ts[tid] += u;
        __syncthreads();
    }
    int ex = ts[tid] - s;
    int base = bbase[bId];
    excl[2 * tid] = ex; excl[2 * tid + 1] = ex + v0;
    cur[2 * tid] = ex;  cur[2 * tid + 1] = ex + v0;
    if (n0 < NN) { rp[n0] = base + ex;      dinv[n0] = rsqrtf((float)v0); }
    if (n1 < NN) { rp[n1] = base + ex + v0; dinv[n1] = rsqrtf((float)v1); }
    __syncthreads();
    for (int i = tid; i < n; i += 256) {
        int pe = e[i];
        int pos = atomicAdd(&cur[pe & 511], 1);
        stage[pos] = pe >> 9;
    }
    // self loop = last slot of each segment
    {
        int t0 = 2 * tid, t1 = 2 * tid + 1;
        if (n0 < NN) stage[excl[t0] + c[t0]] = n0;
        if (n1 < NN) stage[excl[t1] + c[t1]] = n1;
    }
    __syncthreads();
    int total = ts[255];
    for (int i = tid; i < total; i += 256) col[base + i] = stage[i];
}

// ---------------- prep: W1,W2 -> fp16 transposed; BN folds ----------------
// 258 blocks x 128 threads: [0,128): W1t row, [128,256): W2t row, 256: bn1, 257: bn2

__global__ __launch_bounds__(128) void k_prep(const float* __restrict__ W1, const float* __restrict__ W2,
                                              _Float16* __restrict__ Wt1, _Float16* __restrict__ Wt2,
                                              const float* __restrict__ b1, const float* __restrict__ g1,
                                              const float* __restrict__ be1, const float* __restrict__ rm1,
                                              const float* __restrict__ rv1,
                                              const float* __restrict__ b2, const float* __restrict__ g2,
                                              const float* __restrict__ be2, const float* __restrict__ rm2,
                                              const float* __restrict__ rv2,
                                              float* __restrict__ sc1, float* __restrict__ sh1,
                                              float* __restrict__ sc2, float* __restrict__ sh2) {
    int bid = blockIdx.x, t = threadIdx.x;
    if (bid < 128) {
        Wt1[bid * 128 + t] = (_Float16)W1[t * 128 + bid];
    } else if (bid < 256) {
        int nn = bid - 128;
        Wt2[nn * 128 + t] = (_Float16)W2[t * 128 + nn];
    } else if (bid == 256) {
        float sv = g1[t] * rsqrtf(rv1[t] + 1e-5f);
        sc1[t] = sv;
        sh1[t] = (b1[t] - rm1[t]) * sv + be1[t];
    } else {
        float sv = g2[t] * rsqrtf(rv2[t] + 1e-5f);
        sc2[t] = sv;
        sh2[t] = (b2[t] - rm2[t]) * sv + be2[t];
    }
}

// ---------------- MFMA GEMM [N,128]@[128,128], epilogue row*=dinv, out fp16 ----------------
// F32IN: A is fp32 (converted in-register); else fp16.

template <bool F32IN>
__global__ __launch_bounds__(256) void k_gemm_mfma(const void* __restrict__ Ain,
                                                   const _Float16* __restrict__ Wt,
                                                   const float* __restrict__ dinv,
                                                   _Float16* __restrict__ C) {
    __shared__ _Float16 Wl[CH * CH];  // 32 KB, [row][16B-slot XOR-swizzled]
    {
        const float4* wg = (const float4*)Wt;
#pragma unroll
        for (int i = 0; i < 8; ++i) {
            int chunk = i * 256 + threadIdx.x;
            int row = chunk >> 4, slot = chunk & 15;
            float4 v = wg[chunk];
            *(float4*)((char*)Wl + row * 256 + ((slot ^ (row & 15)) * 16)) = v;
        }
    }
    __syncthreads();
    int lane = threadIdx.x & 63;
    int l15 = lane & 15, lhi = lane >> 4;
    int row0 = blockIdx.x * 64 + (threadIdx.x >> 6) * 16;
    if (row0 >= NN) return;

    h8 afrag[4];
    if (F32IN) {
        const float* Arow = (const float*)Ain + (size_t)(row0 + l15) * CH + lhi * 8;
#pragma unroll
        for (int ks = 0; ks < 4; ++ks) {
            float4 a = *(const float4*)(Arow + ks * 32);
            float4 b = *(const float4*)(Arow + ks * 32 + 4);
            h8 o;
            o[0] = (_Float16)a.x; o[1] = (_Float16)a.y; o[2] = (_Float16)a.z; o[3] = (_Float16)a.w;
            o[4] = (_Float16)b.x; o[5] = (_Float16)b.y; o[6] = (_Float16)b.z; o[7] = (_Float16)b.w;
            afrag[ks] = o;
        }
    } else {
        const _Float16* Arow = (const _Float16*)Ain + (size_t)(row0 + l15) * CH + lhi * 8;
#pragma unroll
        for (int ks = 0; ks < 4; ++ks) afrag[ks] = *(const h8*)(Arow + ks * 32);
    }

    f32x4 acc[8] = {};
#pragma unroll
    for (int ks = 0; ks < 4; ++ks) {
        int slot = ks * 4 + lhi;
#pragma unroll
        for (int c = 0; c < 8; ++c) {
            int brow = c * 16 + l15;
            h8 b = *(const h8*)((char*)Wl + brow * 256 + ((slot ^ (brow & 15)) * 16));
            acc[c] = __builtin_amdgcn_mfma_f32_16x16x32_f16(afrag[ks], b, acc[c], 0, 0, 0);
        }
    }
    float dv[4];
#pragma unroll
    for (int j = 0; j < 4; ++j) dv[j] = dinv[row0 + lhi * 4 + j];
#pragma unroll
    for (int c = 0; c < 8; ++c)
#pragma unroll
        for (int j = 0; j < 4; ++j) {
            float v = acc[c][j] * dv[j];
            C[(size_t)(row0 + lhi * 4 + j) * CH + c * 16 + l15] = (_Float16)v;
        }
}

// ---------------- Aggregation, fp16 rows, 8-deep gather pipeline ----------------

__global__ __launch_bounds__(256) void k_agg128h(const _Float16* __restrict__ h, const int* __restrict__ rp,
                                                 const int* __restrict__ col, const float* __restrict__ dinv,
                                                 const float* __restrict__ sc, const float* __restrict__ sh,
                                                 _Float16* __restrict__ out) {
    int node = blockIdx.x * 4 + (threadIdx.x >> 6);
    if (node >= NN) return;
    node = __builtin_amdgcn_readfirstlane(node);
    int lane = threadIdx.x & 63;
    int beg = rp[node], end = rp[node + 1];
    float ax = 0.f, ay = 0.f;
    int e = beg;
    for (; e + 8 <= end; e += 8) {
        int s0 = col[e], s1 = col[e + 1], s2 = col[e + 2], s3 = col[e + 3];
        int s4 = col[e + 4], s5 = col[e + 5], s6 = col[e + 6], s7 = col[e + 7];
        h2 v0 = *(const h2*)(h + (size_t)s0 * CH + lane * 2);
        h2 v1 = *(const h2*)(h + (size_t)s1 * CH + lane * 2);
        h2 v2 = *(const h2*)(h + (size_t)s2 * CH + lane * 2);
        h2 v3 = *(const h2*)(h + (size_t)s3 * CH + lane * 2);
        h2 v4 = *(const h2*)(h + (size_t)s4 * CH + lane * 2);
        h2 v5 = *(const h2*)(h + (size_t)s5 * CH + lane * 2);
        h2 v6 = *(const h2*)(h + (size_t)s6 * CH + lane * 2);
        h2 v7 = *(const h2*)(h + (size_t)s7 * CH + lane * 2);
        ax += ((float)v0[0] + (float)v1[0]) + ((float)v2[0] + (float)v3[0])
            + ((float)v4[0] + (float)v5[0]) + ((float)v6[0] + (float)v7[0]);
        ay += ((float)v0[1] + (float)v1[1]) + ((float)v2[1] + (float)v3[1])
            + ((float)v4[1] + (float)v5[1]) + ((float)v6[1] + (float)v7[1]);
    }
    if (e + 4 <= end) {
        int s0 = col[e], s1 = col[e + 1], s2 = col[e + 2], s3 = col[e + 3];
        h2 v0 = *(const h2*)(h + (size_t)s0 * CH + lane * 2);
        h2 v1 = *(const h2*)(h + (size_t)s1 * CH + lane * 2);
        h2 v2 = *(const h2*)(h + (size_t)s2 * CH + lane * 2);
        h2 v3 = *(const h2*)(h + (size_t)s3 * CH + lane * 2);
        ax += ((float)v0[0] + (float)v1[0]) + ((float)v2[0] + (float)v3[0]);
        ay += ((float)v0[1] + (float)v1[1]) + ((float)v2[1] + (float)v3[1]);
        e += 4;
    }
    for (; e < end; ++e) {
        int s0 = col[e];
        h2 v0 = *(const h2*)(h + (size_t)s0 * CH + lane * 2);
        ax += (float)v0[0];
        ay += (float)v0[1];
    }
    float dvn = dinv[node];
    int c = lane * 2;
    float2 scv = *(const float2*)(sc + c);
    float2 shv = *(const float2*)(sh + c);
    float o0 = fmaxf(fmaf(ax * dvn, scv.x, shv.x), 0.f);
    float o1 = fmaxf(fmaf(ay * dvn, scv.y, shv.y), 0.f);
    h2 o; o[0] = (_Float16)o0; o[1] = (_Float16)o1;
    *(h2*)(out + (size_t)node * CH + c) = o;
}

// ---------------- Layer 3 ----------------

__global__ __launch_bounds__(256) void k_gemm_out(const _Float16* __restrict__ A, const float* __restrict__ W3,
                                                  const float* __restrict__ dinv, float* __restrict__ H3) {
    __shared__ float w3s[256];
    w3s[threadIdx.x] = W3[threadIdx.x];
    __syncthreads();
    int n = blockIdx.x * 256 + threadIdx.x;
    if (n >= NN) return;
    const h8* ar = (const h8*)(A + (size_t)n * CH);
    float a0 = 0.f, a1 = 0.f;
#pragma unroll
    for (int kb = 0; kb < 16; ++kb) {
        h8 a = ar[kb];
#pragma unroll
        for (int j = 0; j < 8; ++j) {
            float av = (float)a[j];
            int k = kb * 8 + j;
            a0 += av * w3s[k * 2];
            a1 += av * w3s[k * 2 + 1];
        }
    }
    float dv = dinv[n];
    *(float2*)(H3 + (size_t)n * 2) = make_float2(a0 * dv, a1 * dv);
}

__global__ __launch_bounds__(256) void k_agg_out(const float* __restrict__ H3, const int* __restrict__ rp,
                                                 const int* __restrict__ col, const float* __restrict__ dinv,
                                                 const float* __restrict__ b3, float* __restrict__ out) {
    int n = blockIdx.x * 256 + threadIdx.x;
    if (n >= NN) return;
    int beg = rp[n], end = rp[n + 1];
    float a0 = 0.f, a1 = 0.f;
    for (int e = beg; e < end; ++e) {
        int s = col[e];
        float2 hv = *(const float2*)(H3 + (size_t)s * 2);
        a0 += hv.x;
        a1 += hv.y;
    }
    float dv = dinv[n];
    out[(size_t)n * 2 + 0] = fmaf(a0, dv, b3[0]);
    out[(size_t)n * 2 + 1] = fmaf(a1, dv, b3[1]);
}

// ---------------- launch ----------------

extern "C" void kernel_launch(void* const* d_in, const int* in_sizes, int n_in,
                              void* d_out, int out_size, void* d_ws, size_t ws_size,
                              hipStream_t stream) {
    const float* x  = (const float*)d_in[0];
    const int* ei   = (const int*)d_in[1];
    const int* src  = ei;
    const int* dst  = ei + EE;
    const float* W1 = (const float*)d_in[2];
    const float* b1 = (const float*)d_in[3];
    const float* g1 = (const float*)d_in[4];
    const float* be1 = (const float*)d_in[5];
    const float* rm1 = (const float*)d_in[6];
    const float* rv1 = (const float*)d_in[7];
    const float* W2 = (const float*)d_in[8];
    const float* b2 = (const float*)d_in[9];
    const float* g2 = (const float*)d_in[10];
    const float* be2 = (const float*)d_in[11];
    const float* rm2 = (const float*)d_in[12];
    const float* rv2 = (const float*)d_in[13];
    const float* W3 = (const float*)d_in[14];
    const float* b3 = (const float*)d_in[15];
    float* out = (float*)d_out;

    char* p = (char*)d_ws;
    auto carve = [&](size_t bytes) -> void* {
        void* r = (void*)p;
        p += (bytes + 255) & ~(size_t)255;
        return r;
    };
    int* rp     = (int*)carve((size_t)(NN + 1) * 4);
    float* dinv = (float*)carve((size_t)NN * 4);
    int* col    = (int*)carve((size_t)(EE + NN) * 4);
    int* bbase  = (int*)carve(256 * 4);
    float* sc1  = (float*)carve(128 * 4);
    float* sh1  = (float*)carve(128 * 4);
    float* sc2  = (float*)carve(128 * 4);
    float* sh2  = (float*)carve(128 * 4);
    _Float16* bufA = (_Float16*)carve((size_t)NN * CH * 2);
    _Float16* bufB = (_Float16*)carve((size_t)NN * CH * 2);
    _Float16* Wt1  = (_Float16*)carve(128 * 128 * 2);
    _Float16* Wt2  = (_Float16*)carve(128 * 128 * 2);
    float* h3   = (float*)carve((size_t)NN * 2 * 4);

    // bucket workspace aliases bufA (dead until first GEMM): 8.03 MB < 25.6 MB
    int* eb   = (int*)bufA;
    int* gcur = eb + (size_t)NBUCK * CAP_E;

    hipMemsetAsync(gcur, 0, (size_t)NBUCK * 4, stream);

    k_passA<<<(EE + 4095) / 4096, 256, 0, stream>>>(src, dst, gcur, eb);
    k_bscan<<<1, 256, 0, stream>>>(gcur, bbase, rp);
    k_passB<<<NBUCK, 256, 0, stream>>>(gcur, eb, bbase, rp, dinv, col);
    k_prep<<<258, 128, 0, stream>>>(W1, W2, Wt1, Wt2,
                                    b1, g1, be1, rm1, rv1,
                                    b2, g2, be2, rm2, rv2,
                                    sc1, sh1, sc2, sh2);

    k_gemm_mfma<true><<<(NN + 63) / 64, 256, 0, stream>>>(x, Wt1, dinv, bufA);
    k_agg128h<<<(NN + 3) / 4, 256, 0, stream>>>(bufA, rp, col, dinv, sc1, sh1, bufB);
    k_gemm_mfma<false><<<(NN + 63) / 64, 256, 0, stream>>>(bufB, Wt2, dinv, bufA);
    k_agg128h<<<(NN + 3) / 4, 256, 0, stream>>>(bufA, rp, col, dinv, sc2, sh2, bufB);
    k_gemm_out<<<(NN + 255) / 256, 256, 0, stream>>>(bufB, W3, dinv, h3);
    k_agg_out<<<(NN + 255) / 256, 256, 0, stream>>>(h3, rp, col, dinv, b3, out);
}